// Round 11
// baseline (216.102 us; speedup 1.0000x reference)
//
#include <hip/hip_runtime.h>
#include <hip/hip_bf16.h>

#define B_ 2
#define T_ 2048
#define C_ 1024
#define H_ 16
#define HD_ 64
#define O_ 1152   // C + 2*HD

#define NX  (B_ * T_ * C_)      // 4194304
#define NW1 (O_ * C_)           // 1179648
#define NW2 (C_ * C_)           // 1048576

// softmax runs in exp2 domain: Q pre-scale = (1/8) * log2(e)
#define QSCALE 0.1803368801111244f

typedef __attribute__((ext_vector_type(8))) short bf16x8;
typedef __attribute__((ext_vector_type(4))) float f32x4;
typedef __attribute__((ext_vector_type(16))) float f32x16;
typedef __attribute__((ext_vector_type(4))) unsigned u32x4;
typedef __attribute__((ext_vector_type(2))) unsigned u32x2;

__device__ inline short f2bf(float f) {
    union { float f; unsigned u; } v; v.f = f;
    unsigned r = v.u + 0x7FFFu + ((v.u >> 16) & 1u);
    return (short)(r >> 16);
}
__device__ inline float bf2f(short s) {
    union { unsigned u; float f; } v; v.u = ((unsigned)(unsigned short)s) << 16;
    return v.f;
}
// native 2^x (v_exp_f32)
__device__ inline float exp2fast(float x) { return __builtin_amdgcn_exp2f(x); }
// packed bf16(lo) | bf16(hi)<<16, RNE
__device__ inline unsigned cvtpk(float lo, float hi) {
    unsigned r;
    asm("v_cvt_pk_bf16_f32 %0, %1, %2" : "=v"(r) : "v"(lo), "v"(hi));
    return r;
}
// permlane32_swap via builtin (hazard-safe; raw inline asm lacks the
// compiler-inserted VALU->permlane wait states and read garbage - round 10).
// Semantics: r[0] = {a.row0 | b.row0}, r[1] = {a.row1 | b.row1}  (vdst.row1 <-> vsrc.row0)
__device__ inline u32x2 pswap(unsigned a, unsigned b) {
    return __builtin_amdgcn_permlane32_swap(a, b, false, false);
}
// cross-half (lane^32) max/add, direction-agnostic: swap(x,x) yields
// {row0-bcast, row1-bcast} in some order; combining both is exact either way.
__device__ inline float xmax32(float x) {
    u32x2 r = pswap(__float_as_uint(x), __float_as_uint(x));
    return fmaxf(__uint_as_float(r[0]), __uint_as_float(r[1]));
}
__device__ inline float xadd32(float x) {
    u32x2 r = pswap(__float_as_uint(x), __float_as_uint(x));
    return __uint_as_float(r[0]) + __uint_as_float(r[1]);
}

// -------- f32 -> bf16 pre-conversion of x, Wqkv, Wproj (one launch) --------
__global__ __launch_bounds__(256) void cvt_bf16(const float* __restrict__ x,
        const float* __restrict__ w1, const float* __restrict__ w2,
        short* __restrict__ xb, short* __restrict__ w1b, short* __restrict__ w2b) {
    size_t i = ((size_t)blockIdx.x * 256 + threadIdx.x) * 8;
    const float* src; short* dst; size_t off;
    if (i < (size_t)NX)              { src = x;  dst = xb;  off = i; }
    else if (i < (size_t)NX + NW1)   { src = w1; dst = w1b; off = i - NX; }
    else                             { src = w2; dst = w2b; off = i - NX - NW1; }
    f32x4 a = *(const f32x4*)(src + off);
    f32x4 b = *(const f32x4*)(src + off + 4);
    bf16x8 r;
    r[0] = f2bf(a[0]); r[1] = f2bf(a[1]); r[2] = f2bf(a[2]); r[3] = f2bf(a[3]);
    r[4] = f2bf(b[0]); r[5] = f2bf(b[1]); r[6] = f2bf(b[2]); r[7] = f2bf(b[3]);
    *(bf16x8*)(dst + off) = r;
}

// C(M,N) = A(M,K) * B(N,K)^T, bf16 inputs, fp32 accum.
// v4: 1-wave blocks, 64x64 tile = 4x4 frags of 16x16x32 -> 16 indep MFMAs :
// 8 loads per k-step with fine-grained packing (1152/1024 blocks, ~4.5/CU).
// XCD swizzle keeps m-panel-sharing blocks on one XCD's L2.
template <bool OUT_BF16>
__global__ __launch_bounds__(64) void gemm_bt(const short* __restrict__ A,
                                              const short* __restrict__ Bm,
                                              void* __restrict__ Cv,
                                              int M, int N, int K) {
    int ntn = N >> 6;
    int nwg = (M >> 6) * ntn;
    int cpx = nwg >> 3;                         // grids are %8 == 0
    int bid = (int)blockIdx.x;
    int swz = (bid % 8) * cpx + bid / 8;        // bijective XCD swizzle
    int m0 = (swz / ntn) << 6;
    int n0 = (swz % ntn) << 6;
    int l = threadIdx.x;
    int c = l & 15, g = l >> 4;

    f32x4 acc[4][4] = {};
    const short* Ap[4];
    const short* Bp[4];
    #pragma unroll
    for (int i = 0; i < 4; i++)
        Ap[i] = A + (size_t)(m0 + i * 16 + c) * K + g * 8;
    #pragma unroll
    for (int j = 0; j < 4; j++)
        Bp[j] = Bm + (size_t)(n0 + j * 16 + c) * K + g * 8;

    #pragma unroll 2
    for (int k0 = 0; k0 < K; k0 += 32) {
        bf16x8 a[4], b[4];
        #pragma unroll
        for (int i = 0; i < 4; i++) a[i] = *(const bf16x8*)(Ap[i] + k0);
        #pragma unroll
        for (int j = 0; j < 4; j++) b[j] = *(const bf16x8*)(Bp[j] + k0);
        #pragma unroll
        for (int i = 0; i < 4; i++)
            #pragma unroll
            for (int j = 0; j < 4; j++)
                acc[i][j] = __builtin_amdgcn_mfma_f32_16x16x32_bf16(a[i], b[j], acc[i][j], 0, 0, 0);
    }

    #pragma unroll
    for (int i = 0; i < 4; i++)
        #pragma unroll
        for (int j = 0; j < 4; j++)
            #pragma unroll
            for (int r = 0; r < 4; r++) {
                int rr = m0 + i * 16 + g * 4 + r;   // C/D row = (l>>4)*4 + reg
                int cc = n0 + j * 16 + c;           // C/D col = l&15
                if (OUT_BF16)
                    ((short*)Cv)[(size_t)rr * N + cc] = f2bf(acc[i][j][r]);
                else
                    ((float*)Cv)[(size_t)rr * N + cc] = acc[i][j][r];
            }
}

// Causal depthwise conv1d (K=3) + bias on bf16 qkv; splits -> Q (B,H,T,64,
// scaled QSCALE for exp2-domain softmax), K (B,T,64), V transposed (B,64,T).
__global__ __launch_bounds__(256) void conv_split(const short* __restrict__ qkv,
        const float* __restrict__ qw, const float* __restrict__ qb,
        const float* __restrict__ kw, const float* __restrict__ kbias,
        const float* __restrict__ vw, const float* __restrict__ vbias,
        short* __restrict__ Qs, short* __restrict__ Kb, short* __restrict__ Vt) {
    int idx = blockIdx.x * 256 + threadIdx.x;
    int ch = idx % O_;
    int bt = idx / O_;
    int t = bt % T_;
    int b = bt / T_;
    const short* p = qkv + (size_t)bt * O_ + ch;
    float x2 = bf2f(p[0]);
    float x1 = (t >= 1) ? bf2f(p[-O_]) : 0.f;
    float x0 = (t >= 2) ? bf2f(p[-2 * O_]) : 0.f;
    float w0, w1, w2, bias;
    if (ch < C_)             { w0 = qw[ch*3]; w1 = qw[ch*3+1]; w2 = qw[ch*3+2]; bias = qb[ch]; }
    else if (ch < C_ + HD_)  { int cc = ch - C_;       w0 = kw[cc*3]; w1 = kw[cc*3+1]; w2 = kw[cc*3+2]; bias = kbias[cc]; }
    else                     { int cc = ch - C_ - HD_; w0 = vw[cc*3]; w1 = vw[cc*3+1]; w2 = vw[cc*3+2]; bias = vbias[cc]; }
    float y = fmaf(x0, w0, fmaf(x1, w1, fmaf(x2, w2, bias)));
    if (ch < C_) {
        int h = ch >> 6, d = ch & 63;
        Qs[(((size_t)b * H_ + h) * T_ + t) * HD_ + d] = f2bf(y * QSCALE);
    } else if (ch < C_ + HD_) {
        Kb[((size_t)b * T_ + t) * HD_ + (ch - C_)] = f2bf(y);
    } else {
        Vt[((size_t)b * HD_ + (ch - C_ - HD_)) * T_ + t] = f2bf(y);
    }
}

// Flash-style causal MQA, v6: swapped QK^T (32x32x16), exp2-domain softmax,
// tree reductions, defer-max (T13), permlane32_swap BUILTIN for all lane^32
// traffic (T12). 1-wave blocks (zero intra-block idle), qt = 63-bid (heavy
// first), 2048 blocks.
// C/D layout (m74-verified): col=lane&31, row=(reg&3)+8*(reg>>2)+4*(lane>>5).
__global__ __launch_bounds__(64) void attn_kernel(const short* __restrict__ Qs,
        const short* __restrict__ Kb, const short* __restrict__ Vt,
        short* __restrict__ Y) {
    int bh = blockIdx.y;
    int b = bh >> 4;
    int h = bh & 15;
    int l = threadIdx.x;
    int ql = l & 31, hi = l >> 5;
    int qt = 63 - (int)blockIdx.x;             // heavy first
    int qbase = qt * 32;
    int qi = qbase + ql;

    // Q B-fragments, 4 contraction steps of 16 over HD=64 (col=q=ql, d=hi*8+j)
    const short* Qp = Qs + ((size_t)bh * T_ + qi) * HD_ + hi * 8;
    bf16x8 qf[4];
    #pragma unroll
    for (int s = 0; s < 4; s++) qf[s] = *(const bf16x8*)(Qp + s * 16);

    f32x16 Oa0 = {}, Oa1 = {};                 // O^T, d-blocks [0,32) and [32,64)
    float mrow = -1e30f, lsum = 0.f;

    const short* Kbase = Kb + (size_t)b * T_ * HD_;
    const short* Vbase = Vt + (size_t)b * HD_ * T_;

    int nt = (qt >> 1) + 1;
    for (int it = 0; it < nt; it++) {
        int kt0 = it * 64;
        // ---- S^T: two 32-row k-subtiles, contraction over d ----
        f32x16 sv0 = {}, sv1 = {};
        #pragma unroll
        for (int s = 0; s < 4; s++) {
            bf16x8 ka = *(const bf16x8*)(Kbase + (size_t)(kt0 + ql) * HD_ + s * 16 + hi * 8);
            sv0 = __builtin_amdgcn_mfma_f32_32x32x16_bf16(ka, qf[s], sv0, 0, 0, 0);
        }
        #pragma unroll
        for (int s = 0; s < 4; s++) {
            bf16x8 ka = *(const bf16x8*)(Kbase + (size_t)(kt0 + 32 + ql) * HD_ + s * 16 + hi * 8);
            sv1 = __builtin_amdgcn_mfma_f32_32x32x16_bf16(ka, qf[s], sv1, 0, 0, 0);
        }
        // ---- causal mask (last tile only; scale folded into Q) ----
        if (kt0 + 64 > qbase) {
            #pragma unroll
            for (int r = 0; r < 16; r++) {
                int kl = (r & 3) + 8 * (r >> 2) + 4 * hi;
                if (kt0 + kl > qi)      sv0[r] = -1e30f;
                if (kt0 + 32 + kl > qi) sv1[r] = -1e30f;
            }
        }
        // ---- row max: depth-5 tree + cross-half combine ----
        float t8[8];
        #pragma unroll
        for (int r = 0; r < 8; r++)
            t8[r] = fmaxf(fmaxf(sv0[r], sv0[r + 8]), fmaxf(sv1[r], sv1[r + 8]));
        float pmax = fmaxf(fmaxf(fmaxf(t8[0], t8[4]), fmaxf(t8[1], t8[5])),
                           fmaxf(fmaxf(t8[2], t8[6]), fmaxf(t8[3], t8[7])));
        pmax = xmax32(pmax);
        // ---- defer-max (T13): rescale only when max grew past THR=8 ----
        if (!__all(pmax <= mrow + 8.f)) {
            float nm = fmaxf(mrow, pmax);
            float alpha = exp2fast(mrow - nm);
            mrow = nm;
            lsum *= alpha;
            #pragma unroll
            for (int r = 0; r < 16; r++) { Oa0[r] *= alpha; Oa1[r] *= alpha; }
        }
        // ---- P = exp2(S - m); sum via depth-5 tree + cross-half add ----
        #pragma unroll
        for (int r = 0; r < 16; r++) sv0[r] = exp2fast(sv0[r] - mrow);
        #pragma unroll
        for (int r = 0; r < 16; r++) sv1[r] = exp2fast(sv1[r] - mrow);
        float s8[8];
        #pragma unroll
        for (int r = 0; r < 8; r++)
            s8[r] = (sv0[r] + sv0[r + 8]) + (sv1[r] + sv1[r + 8]);
        float psum = ((s8[0] + s8[4]) + (s8[1] + s8[5])) +
                     ((s8[2] + s8[6]) + (s8[3] + s8[7]));
        lsum += xadd32(psum);
        // ---- P redistribution: cvt_pk + permlane32_swap builtin ----
        // r02 = pswap(X0,X2): r02[0] = {own X0 | partner X2} = pw.u[0]
        //                     r02[1] = {partner X0 | own X2} = pw.u[2]
        #pragma unroll
        for (int sub = 0; sub < 2; sub++) {
            #pragma unroll
            for (int hh = 0; hh < 2; hh++) {
                unsigned X0, X1, X2, X3;
                if (sub == 0) {
                    X0 = cvtpk(sv0[hh * 8 + 0], sv0[hh * 8 + 1]);
                    X1 = cvtpk(sv0[hh * 8 + 2], sv0[hh * 8 + 3]);
                    X2 = cvtpk(sv0[hh * 8 + 4], sv0[hh * 8 + 5]);
                    X3 = cvtpk(sv0[hh * 8 + 6], sv0[hh * 8 + 7]);
                } else {
                    X0 = cvtpk(sv1[hh * 8 + 0], sv1[hh * 8 + 1]);
                    X1 = cvtpk(sv1[hh * 8 + 2], sv1[hh * 8 + 3]);
                    X2 = cvtpk(sv1[hh * 8 + 4], sv1[hh * 8 + 5]);
                    X3 = cvtpk(sv1[hh * 8 + 6], sv1[hh * 8 + 7]);
                }
                u32x2 r02 = pswap(X0, X2);
                u32x2 r13 = pswap(X1, X3);
                union { u32x4 u; bf16x8 v; } pw;
                pw.u[0] = r02[0];   // k elems (hi*8 + 0,1)
                pw.u[1] = r13[0];   // k elems (hi*8 + 2,3)
                pw.u[2] = r02[1];   // k elems (hi*8 + 4,5)
                pw.u[3] = r13[1];   // k elems (hi*8 + 6,7)
                int koff = kt0 + sub * 32 + hh * 16 + hi * 8;
                bf16x8 va0 = *(const bf16x8*)(Vbase + (size_t)ql * T_ + koff);
                bf16x8 va1 = *(const bf16x8*)(Vbase + (size_t)(32 + ql) * T_ + koff);
                Oa0 = __builtin_amdgcn_mfma_f32_32x32x16_bf16(va0, pw.v, Oa0, 0, 0, 0);
                Oa1 = __builtin_amdgcn_mfma_f32_32x32x16_bf16(va1, pw.v, Oa1, 0, 0, 0);
            }
        }
    }
    // ---- epilogue: normalize, write one Y-row segment per lane ----
    float inv = 1.f / lsum;
    size_t orow = ((size_t)b * T_ + qi) * C_ + h * HD_;
    #pragma unroll
    for (int r = 0; r < 16; r += 2) {
        int d = (r & 3) + 8 * (r >> 2) + 4 * hi;       // r even -> d even; (r,r+1)->(d,d+1)
        *(unsigned*)(Y + orow + d)      = cvtpk(Oa0[r] * inv, Oa0[r + 1] * inv);
        *(unsigned*)(Y + orow + 32 + d) = cvtpk(Oa1[r] * inv, Oa1[r + 1] * inv);
    }
}

extern "C" void kernel_launch(void* const* d_in, const int* in_sizes, int n_in,
                              void* d_out, int out_size, void* d_ws, size_t ws_size,
                              hipStream_t stream) {
    const float* x     = (const float*)d_in[0];
    const float* Wqkv  = (const float*)d_in[1];
    const float* qw    = (const float*)d_in[2];
    const float* qb    = (const float*)d_in[3];
    const float* kw    = (const float*)d_in[4];
    const float* kbias = (const float*)d_in[5];
    const float* vw    = (const float*)d_in[6];
    const float* vbias = (const float*)d_in[7];
    const float* Wproj = (const float*)d_in[8];

    char* ws = (char*)d_ws;
    short* xb     = (short*)ws;                    //  8388608 B (reused as Ybf later)
    short* Wqkvb  = (short*)(ws + 8388608);        //  2359296 B
    short* Wprojb = (short*)(ws + 10747904);       //  2097152 B
    short* qkvb   = (short*)(ws + 12845056);       //  9437184 B
    short* Qsc    = (short*)(ws + 22282240);       //  8388608 B
    short* Kbf    = (short*)(ws + 30670848);       //   524288 B
    short* Vtr    = (short*)(ws + 31195136);       //   524288 B  (total 31.7 MB)
    short* Ybf    = xb;                            // x dead after gemm1

    const int M = B_ * T_;  // 4096

    // 0) f32 -> bf16: x, Wqkv, Wproj
    cvt_bf16<<<dim3(3136), 256, 0, stream>>>(x, Wqkv, Wproj, xb, Wqkvb, Wprojb);

    // 1) qkv = x @ Wqkv^T  (bf16 out)   grid 64*18 = 1152 (%8==0)
    gemm_bt<true><<<dim3((M / 64) * (O_ / 64)), 64, 0, stream>>>(
        xb, Wqkvb, qkvb, M, O_, C_);

    // 2) causal dwconv + split + scale + V-transpose
    conv_split<<<dim3((B_ * T_ * O_) / 256), 256, 0, stream>>>(
        qkvb, qw, qb, kw, kbias, vw, vbias, Qsc, Kbf, Vtr);

    // 3) causal MQA attention -> y (B,T,C) bf16
    attn_kernel<<<dim3(64, B_ * H_), 64, 0, stream>>>(Qsc, Kbf, Vtr, Ybf);

    // 4) out = y @ Wproj^T -> f32 d_out   grid 64*16 = 1024 (%8==0)
    gemm_bt<false><<<dim3((M / 64) * (C_ / 64)), 64, 0, stream>>>(
        Ybf, Wprojb, (float*)d_out, M, C_, C_);
}

// Round 12
// 168.550 us; speedup vs baseline: 1.2821x; 1.2821x over previous
//
#include <hip/hip_runtime.h>
#include <hip/hip_bf16.h>

#define B_ 2
#define T_ 2048
#define C_ 1024
#define H_ 16
#define HD_ 64
#define O_ 1152   // C + 2*HD

#define NX  (B_ * T_ * C_)      // 4194304
#define NW1 (O_ * C_)           // 1179648
#define NW2 (C_ * C_)           // 1048576

// softmax runs in exp2 domain: Q pre-scale = (1/8) * log2(e)
#define QSCALE 0.1803368801111244f

typedef __attribute__((ext_vector_type(8))) short bf16x8;
typedef __attribute__((ext_vector_type(4))) float f32x4;
typedef __attribute__((ext_vector_type(16))) float f32x16;
typedef __attribute__((ext_vector_type(4))) unsigned u32x4;
typedef __attribute__((ext_vector_type(2))) unsigned u32x2;

__device__ inline short f2bf(float f) {
    union { float f; unsigned u; } v; v.f = f;
    unsigned r = v.u + 0x7FFFu + ((v.u >> 16) & 1u);
    return (short)(r >> 16);
}
__device__ inline float bf2f(short s) {
    union { unsigned u; float f; } v; v.u = ((unsigned)(unsigned short)s) << 16;
    return v.f;
}
// native 2^x (v_exp_f32)
__device__ inline float exp2fast(float x) { return __builtin_amdgcn_exp2f(x); }
// packed bf16(lo) | bf16(hi)<<16, RNE
__device__ inline unsigned cvtpk(float lo, float hi) {
    unsigned r;
    asm("v_cvt_pk_bf16_f32 %0, %1, %2" : "=v"(r) : "v"(lo), "v"(hi));
    return r;
}
// permlane32_swap via builtin (hazard-safe: compiler inserts the required
// VALU->permlane wait states; raw inline asm did not - round 10 failure).
__device__ inline u32x2 pswap(unsigned a, unsigned b) {
    return __builtin_amdgcn_permlane32_swap(a, b, false, false);
}
// cross-half (lane^32) max/add, direction-agnostic
__device__ inline float xmax32(float x) {
    u32x2 r = pswap(__float_as_uint(x), __float_as_uint(x));
    return fmaxf(__uint_as_float(r[0]), __uint_as_float(r[1]));
}
__device__ inline float xadd32(float x) {
    u32x2 r = pswap(__float_as_uint(x), __float_as_uint(x));
    return __uint_as_float(r[0]) + __uint_as_float(r[1]);
}

// -------- f32 -> bf16 pre-conversion of x, Wqkv, Wproj (one launch) --------
__global__ __launch_bounds__(256) void cvt_bf16(const float* __restrict__ x,
        const float* __restrict__ w1, const float* __restrict__ w2,
        short* __restrict__ xb, short* __restrict__ w1b, short* __restrict__ w2b) {
    size_t i = ((size_t)blockIdx.x * 256 + threadIdx.x) * 8;
    const float* src; short* dst; size_t off;
    if (i < (size_t)NX)              { src = x;  dst = xb;  off = i; }
    else if (i < (size_t)NX + NW1)   { src = w1; dst = w1b; off = i - NX; }
    else                             { src = w2; dst = w2b; off = i - NX - NW1; }
    f32x4 a = *(const f32x4*)(src + off);
    f32x4 b = *(const f32x4*)(src + off + 4);
    bf16x8 r;
    r[0] = f2bf(a[0]); r[1] = f2bf(a[1]); r[2] = f2bf(a[2]); r[3] = f2bf(a[3]);
    r[4] = f2bf(b[0]); r[5] = f2bf(b[1]); r[6] = f2bf(b[2]); r[7] = f2bf(b[3]);
    *(bf16x8*)(dst + off) = r;
}

// C(M,N) = A(M,K) * B(N,K)^T, bf16 inputs, fp32 accum.
// v5: 1-wave blocks, 64x64 tile, 16 MFMA : 8 loads per k-step, PLUS k-step
// register double-buffer: next step's a/b issued before this step's MFMAs,
// so load latency hides under 16 MFMAs instead of serializing.
template <bool OUT_BF16>
__global__ __launch_bounds__(64) void gemm_bt(const short* __restrict__ A,
                                              const short* __restrict__ Bm,
                                              void* __restrict__ Cv,
                                              int M, int N, int K) {
    int ntn = N >> 6;
    int nwg = (M >> 6) * ntn;
    int cpx = nwg >> 3;                         // grids are %8 == 0
    int bid = (int)blockIdx.x;
    int swz = (bid % 8) * cpx + bid / 8;        // bijective XCD swizzle
    int m0 = (swz / ntn) << 6;
    int n0 = (swz % ntn) << 6;
    int l = threadIdx.x;
    int c = l & 15, g = l >> 4;

    f32x4 acc[4][4] = {};
    const short* Ap[4];
    const short* Bp[4];
    #pragma unroll
    for (int i = 0; i < 4; i++)
        Ap[i] = A + (size_t)(m0 + i * 16 + c) * K + g * 8;
    #pragma unroll
    for (int j = 0; j < 4; j++)
        Bp[j] = Bm + (size_t)(n0 + j * 16 + c) * K + g * 8;

    bf16x8 a[4], b[4], a2[4], b2[4];
    #pragma unroll
    for (int i = 0; i < 4; i++) { a[i] = *(const bf16x8*)Ap[i]; b[i] = *(const bf16x8*)Bp[i]; }

    for (int k0 = 0; k0 < K; k0 += 32) {
        int kn = (k0 + 32 < K) ? (k0 + 32) : k0;   // last iter: harmless reload
        #pragma unroll
        for (int i = 0; i < 4; i++) {
            a2[i] = *(const bf16x8*)(Ap[i] + kn);
            b2[i] = *(const bf16x8*)(Bp[i] + kn);
        }
        #pragma unroll
        for (int i = 0; i < 4; i++)
            #pragma unroll
            for (int j = 0; j < 4; j++)
                acc[i][j] = __builtin_amdgcn_mfma_f32_16x16x32_bf16(a[i], b[j], acc[i][j], 0, 0, 0);
        #pragma unroll
        for (int i = 0; i < 4; i++) { a[i] = a2[i]; b[i] = b2[i]; }
    }

    #pragma unroll
    for (int i = 0; i < 4; i++)
        #pragma unroll
        for (int j = 0; j < 4; j++)
            #pragma unroll
            for (int r = 0; r < 4; r++) {
                int rr = m0 + i * 16 + g * 4 + r;   // C/D row = (l>>4)*4 + reg
                int cc = n0 + j * 16 + c;           // C/D col = l&15
                if (OUT_BF16)
                    ((short*)Cv)[(size_t)rr * N + cc] = f2bf(acc[i][j][r]);
                else
                    ((float*)Cv)[(size_t)rr * N + cc] = acc[i][j][r];
            }
}

// Causal depthwise conv1d (K=3) + bias on bf16 qkv; splits -> Q (B,H,T,64,
// scaled QSCALE for exp2-domain softmax), K (B,T,64), V transposed (B,64,T).
__global__ __launch_bounds__(256) void conv_split(const short* __restrict__ qkv,
        const float* __restrict__ qw, const float* __restrict__ qb,
        const float* __restrict__ kw, const float* __restrict__ kbias,
        const float* __restrict__ vw, const float* __restrict__ vbias,
        short* __restrict__ Qs, short* __restrict__ Kb, short* __restrict__ Vt) {
    int idx = blockIdx.x * 256 + threadIdx.x;
    int ch = idx % O_;
    int bt = idx / O_;
    int t = bt % T_;
    int b = bt / T_;
    const short* p = qkv + (size_t)bt * O_ + ch;
    float x2 = bf2f(p[0]);
    float x1 = (t >= 1) ? bf2f(p[-O_]) : 0.f;
    float x0 = (t >= 2) ? bf2f(p[-2 * O_]) : 0.f;
    float w0, w1, w2, bias;
    if (ch < C_)             { w0 = qw[ch*3]; w1 = qw[ch*3+1]; w2 = qw[ch*3+2]; bias = qb[ch]; }
    else if (ch < C_ + HD_)  { int cc = ch - C_;       w0 = kw[cc*3]; w1 = kw[cc*3+1]; w2 = kw[cc*3+2]; bias = kbias[cc]; }
    else                     { int cc = ch - C_ - HD_; w0 = vw[cc*3]; w1 = vw[cc*3+1]; w2 = vw[cc*3+2]; bias = vbias[cc]; }
    float y = fmaf(x0, w0, fmaf(x1, w1, fmaf(x2, w2, bias)));
    if (ch < C_) {
        int h = ch >> 6, d = ch & 63;
        Qs[(((size_t)b * H_ + h) * T_ + t) * HD_ + d] = f2bf(y * QSCALE);
    } else if (ch < C_ + HD_) {
        Kb[((size_t)b * T_ + t) * HD_ + (ch - C_)] = f2bf(y);
    } else {
        Vt[((size_t)b * HD_ + (ch - C_ - HD_)) * T_ + t] = f2bf(y);
    }
}

// Flash-style causal MQA, v7: round-9's 4-wave sum-balanced blocks (the
// structure that measured 77us) + permlane32_swap (T12) + exp2-domain
// softmax + tree reductions + defer-max (T13) + K-TILE REGISTER PREFETCH:
// next tile's 8 x bf16x8 K loads issue right after this tile's QK MFMAs,
// flying during softmax+PV (~800 cyc) so the next QK never stalls on L2.
// C/D layout (m74-verified): col=lane&31, row=(reg&3)+8*(reg>>2)+4*(lane>>5).
__global__ __launch_bounds__(256) void attn_kernel(const short* __restrict__ Qs,
        const short* __restrict__ Kb, const short* __restrict__ Vt,
        short* __restrict__ Y) {
    int bh = blockIdx.y;
    int b = bh >> 4;
    int h = bh & 15;
    int wid = threadIdx.x >> 6, l = threadIdx.x & 63;
    int ql = l & 31, hi = l >> 5;
    int k2 = blockIdx.x;                       // 0..15
    int qt = (wid < 2) ? (2 * k2 + wid) : (63 - 2 * k2 - (wid & 1));
    int qbase = qt * 32;
    int qi = qbase + ql;

    // Q B-fragments, 4 contraction steps of 16 over HD=64 (col=q=ql, d=hi*8+j)
    const short* Qp = Qs + ((size_t)bh * T_ + qi) * HD_ + hi * 8;
    bf16x8 qf[4];
    #pragma unroll
    for (int s = 0; s < 4; s++) qf[s] = *(const bf16x8*)(Qp + s * 16);

    f32x16 Oa0 = {}, Oa1 = {};                 // O^T, d-blocks [0,32) and [32,64)
    float mrow = -1e30f, lsum = 0.f;

    const short* Kbase = Kb + (size_t)b * T_ * HD_;
    const short* Vbase = Vt + (size_t)b * HD_ * T_;

    auto LDK = [&](int kt, bf16x8 (&dst)[8]) {
        #pragma unroll
        for (int s = 0; s < 4; s++) {
            dst[s]     = *(const bf16x8*)(Kbase + (size_t)(kt + ql) * HD_ + s * 16 + hi * 8);
            dst[4 + s] = *(const bf16x8*)(Kbase + (size_t)(kt + 32 + ql) * HD_ + s * 16 + hi * 8);
        }
    };

    int nt = (qt >> 1) + 1;
    bf16x8 ka[8], kb2[8];
    LDK(0, ka);
    for (int it = 0; it < nt; it++) {
        int kt0 = it * 64;
        // ---- S^T from prefetched K ----
        f32x16 sv0 = {}, sv1 = {};
        #pragma unroll
        for (int s = 0; s < 4; s++)
            sv0 = __builtin_amdgcn_mfma_f32_32x32x16_bf16(ka[s], qf[s], sv0, 0, 0, 0);
        #pragma unroll
        for (int s = 0; s < 4; s++)
            sv1 = __builtin_amdgcn_mfma_f32_32x32x16_bf16(ka[4 + s], qf[s], sv1, 0, 0, 0);
        // ---- issue next tile's K loads (fly during softmax + PV) ----
        int itn = (it + 1 < nt) ? (it + 1) : it;
        LDK(itn * 64, kb2);
        // ---- causal mask (last tile only; scale folded into Q) ----
        if (kt0 + 64 > qbase) {
            #pragma unroll
            for (int r = 0; r < 16; r++) {
                int kl = (r & 3) + 8 * (r >> 2) + 4 * hi;
                if (kt0 + kl > qi)      sv0[r] = -1e30f;
                if (kt0 + 32 + kl > qi) sv1[r] = -1e30f;
            }
        }
        // ---- row max: depth-5 tree + cross-half combine ----
        float t8[8];
        #pragma unroll
        for (int r = 0; r < 8; r++)
            t8[r] = fmaxf(fmaxf(sv0[r], sv0[r + 8]), fmaxf(sv1[r], sv1[r + 8]));
        float pmax = fmaxf(fmaxf(fmaxf(t8[0], t8[4]), fmaxf(t8[1], t8[5])),
                           fmaxf(fmaxf(t8[2], t8[6]), fmaxf(t8[3], t8[7])));
        pmax = xmax32(pmax);
        // ---- defer-max (T13): rescale only when max grew past THR=8 ----
        if (!__all(pmax <= mrow + 8.f)) {
            float nm = fmaxf(mrow, pmax);
            float alpha = exp2fast(mrow - nm);
            mrow = nm;
            lsum *= alpha;
            #pragma unroll
            for (int r = 0; r < 16; r++) { Oa0[r] *= alpha; Oa1[r] *= alpha; }
        }
        // ---- P = exp2(S - m); sum via depth-5 tree + cross-half add ----
        #pragma unroll
        for (int r = 0; r < 16; r++) sv0[r] = exp2fast(sv0[r] - mrow);
        #pragma unroll
        for (int r = 0; r < 16; r++) sv1[r] = exp2fast(sv1[r] - mrow);
        float s8[8];
        #pragma unroll
        for (int r = 0; r < 8; r++)
            s8[r] = (sv0[r] + sv0[r + 8]) + (sv1[r] + sv1[r + 8]);
        float psum = ((s8[0] + s8[4]) + (s8[1] + s8[5])) +
                     ((s8[2] + s8[6]) + (s8[3] + s8[7]));
        lsum += xadd32(psum);
        // ---- P redistribution: cvt_pk + permlane32_swap ----
        #pragma unroll
        for (int sub = 0; sub < 2; sub++) {
            #pragma unroll
            for (int hh = 0; hh < 2; hh++) {
                unsigned X0, X1, X2, X3;
                if (sub == 0) {
                    X0 = cvtpk(sv0[hh * 8 + 0], sv0[hh * 8 + 1]);
                    X1 = cvtpk(sv0[hh * 8 + 2], sv0[hh * 8 + 3]);
                    X2 = cvtpk(sv0[hh * 8 + 4], sv0[hh * 8 + 5]);
                    X3 = cvtpk(sv0[hh * 8 + 6], sv0[hh * 8 + 7]);
                } else {
                    X0 = cvtpk(sv1[hh * 8 + 0], sv1[hh * 8 + 1]);
                    X1 = cvtpk(sv1[hh * 8 + 2], sv1[hh * 8 + 3]);
                    X2 = cvtpk(sv1[hh * 8 + 4], sv1[hh * 8 + 5]);
                    X3 = cvtpk(sv1[hh * 8 + 6], sv1[hh * 8 + 7]);
                }
                u32x2 r02 = pswap(X0, X2);
                u32x2 r13 = pswap(X1, X3);
                union { u32x4 u; bf16x8 v; } pw;
                pw.u[0] = r02[0];   // k elems (hi*8 + 0,1)
                pw.u[1] = r13[0];   // k elems (hi*8 + 2,3)
                pw.u[2] = r02[1];   // k elems (hi*8 + 4,5)
                pw.u[3] = r13[1];   // k elems (hi*8 + 6,7)
                int koff = kt0 + sub * 32 + hh * 16 + hi * 8;
                bf16x8 va0 = *(const bf16x8*)(Vbase + (size_t)ql * T_ + koff);
                bf16x8 va1 = *(const bf16x8*)(Vbase + (size_t)(32 + ql) * T_ + koff);
                Oa0 = __builtin_amdgcn_mfma_f32_32x32x16_bf16(va0, pw.v, Oa0, 0, 0, 0);
                Oa1 = __builtin_amdgcn_mfma_f32_32x32x16_bf16(va1, pw.v, Oa1, 0, 0, 0);
            }
        }
        // ---- rotate prefetch buffer ----
        #pragma unroll
        for (int s = 0; s < 8; s++) ka[s] = kb2[s];
    }
    // ---- epilogue: normalize, write one Y-row segment per lane ----
    float inv = 1.f / lsum;
    size_t orow = ((size_t)b * T_ + qi) * C_ + h * HD_;
    #pragma unroll
    for (int r = 0; r < 16; r += 2) {
        int d = (r & 3) + 8 * (r >> 2) + 4 * hi;       // r even -> d even; (r,r+1)->(d,d+1)
        *(unsigned*)(Y + orow + d)      = cvtpk(Oa0[r] * inv, Oa0[r + 1] * inv);
        *(unsigned*)(Y + orow + 32 + d) = cvtpk(Oa1[r] * inv, Oa1[r + 1] * inv);
    }
}

extern "C" void kernel_launch(void* const* d_in, const int* in_sizes, int n_in,
                              void* d_out, int out_size, void* d_ws, size_t ws_size,
                              hipStream_t stream) {
    const float* x     = (const float*)d_in[0];
    const float* Wqkv  = (const float*)d_in[1];
    const float* qw    = (const float*)d_in[2];
    const float* qb    = (const float*)d_in[3];
    const float* kw    = (const float*)d_in[4];
    const float* kbias = (const float*)d_in[5];
    const float* vw    = (const float*)d_in[6];
    const float* vbias = (const float*)d_in[7];
    const float* Wproj = (const float*)d_in[8];

    char* ws = (char*)d_ws;
    short* xb     = (short*)ws;                    //  8388608 B (reused as Ybf later)
    short* Wqkvb  = (short*)(ws + 8388608);        //  2359296 B
    short* Wprojb = (short*)(ws + 10747904);       //  2097152 B
    short* qkvb   = (short*)(ws + 12845056);       //  9437184 B
    short* Qsc    = (short*)(ws + 22282240);       //  8388608 B
    short* Kbf    = (short*)(ws + 30670848);       //   524288 B
    short* Vtr    = (short*)(ws + 31195136);       //   524288 B  (total 31.7 MB)
    short* Ybf    = xb;                            // x dead after gemm1

    const int M = B_ * T_;  // 4096

    // 0) f32 -> bf16: x, Wqkv, Wproj
    cvt_bf16<<<dim3(3136), 256, 0, stream>>>(x, Wqkv, Wproj, xb, Wqkvb, Wprojb);

    // 1) qkv = x @ Wqkv^T  (bf16 out)   grid 64*18 = 1152 (%8==0)
    gemm_bt<true><<<dim3((M / 64) * (O_ / 64)), 64, 0, stream>>>(
        xb, Wqkvb, qkvb, M, O_, C_);

    // 2) causal dwconv + split + scale + V-transpose
    conv_split<<<dim3((B_ * T_ * O_) / 256), 256, 0, stream>>>(
        qkvb, qw, qb, kw, kbias, vw, vbias, Qsc, Kbf, Vtr);

    // 3) causal MQA attention -> y (B,T,C) bf16
    attn_kernel<<<dim3(16, B_ * H_), 256, 0, stream>>>(Qsc, Kbf, Vtr, Ybf);

    // 4) out = y @ Wproj^T -> f32 d_out   grid 64*16 = 1024 (%8==0)
    gemm_bt<false><<<dim3((M / 64) * (C_ / 64)), 64, 0, stream>>>(
        Ybf, Wprojb, (float*)d_out, M, C_, C_);
}